// Round 6
// baseline (1580.096 us; speedup 1.0000x reference)
//
#include <hip/hip_runtime.h>
#include <math.h>

// Problem constants (from reference)
constexpr int NN  = 100000;   // nodes
constexpr int EE  = 1600000;  // edges
constexpr int IND = 128;      // input dim
constexpr int HID = 64;       // hidden dim

constexpr int NBUCK = (NN + 127) / 128;   // 782 buckets of 128 nodes
constexpr int CAP   = 2432;               // bucket capacity: mean 2046, 8.5-sigma margin
constexpr int CHUNK = 4096;               // edges per multisplit block

// ---------------- small zero ----------------

__global__ __launch_bounds__(256) void k_zero(int* __restrict__ p, int n) {
    int i = blockIdx.x * 256 + threadIdx.x;
    if (i < n) p[i] = 0;
}

// ---------------- bucketized multisplit (replaces hist/scan/permute) --------
// Packs (row<<7)|(col&127) into bucket (col>>7)'s region of ebuf.
// Per-chunk LDS histogram -> 1 global atomic per non-empty bucket (run
// reservation) -> ranked writes. Run-clustered writes keep bucket-tail
// lines L2-hot (kills the 16x partial-line write amplification of the
// node-granular counting sort).

__global__ __launch_bounds__(256) void k_bscatter(const int* __restrict__ row, const int* __restrict__ col,
                                                  int* __restrict__ gcur, int* __restrict__ ebuf) {
    __shared__ int lhist[NBUCK];
    __shared__ int lbase[NBUCK];
    __shared__ int lcur[NBUCK];
    const int tx = threadIdx.x;
    const int cbase = blockIdx.x * CHUNK;

    for (int b = tx; b < NBUCK; b += 256) lhist[b] = 0;
    __syncthreads();

    #pragma unroll
    for (int i = 0; i < CHUNK / 256; ++i) {
        int e = cbase + tx + i * 256;
        if (e < EE) atomicAdd(&lhist[col[e] >> 7], 1);
    }
    __syncthreads();

    for (int b = tx; b < NBUCK; b += 256) {
        int c = lhist[b];
        if (c) lbase[b] = atomicAdd(&gcur[b], c);
        lcur[b] = 0;
    }
    __syncthreads();

    #pragma unroll
    for (int i = 0; i < CHUNK / 256; ++i) {
        int e = cbase + tx + i * 256;
        if (e < EE) {
            int c = col[e];
            int b = c >> 7;
            int rank = atomicAdd(&lcur[b], 1);
            ebuf[b * CAP + lbase[b] + rank] = (row[e] << 7) | (c & 127);
        }
    }
}

// ---------------- per-bucket degree -> dinv ---------------------------------

__global__ __launch_bounds__(256) void k_deg(const int* __restrict__ gcur, const int* __restrict__ ebuf,
                                             float* __restrict__ dinv) {
    __shared__ int h[128];
    const int tx = threadIdx.x;
    const int b = blockIdx.x;
    if (tx < 128) h[tx] = 0;
    __syncthreads();
    const int cnt = gcur[b];
    const int* eb = ebuf + b * CAP;
    for (int e = tx; e < cnt; e += 256) atomicAdd(&h[eb[e] & 127], 1);
    __syncthreads();
    if (tx < 128) {
        int g = b * 128 + tx;
        if (g < NN) dinv[g] = rsqrtf((float)(h[tx] + 1));   // +1 = self-loop
    }
}

// ---------------- fc: h = x @ fc_w + fc_b  (128 -> 64) ----------------------
// A streamed from global (duplicate lane addresses coalesce); B in LDS;
// #pragma unroll 1 bounds VGPR (round-4 spill lesson).

__global__ __launch_bounds__(256) void k_fc(const float* __restrict__ x, const float* __restrict__ w,
                                            const float* __restrict__ b, float* __restrict__ h) {
    __shared__ float sw[IND * HID];     // 32 KB  [k][c]
    const int tx = threadIdx.x;
    for (int i = tx; i < IND * HID; i += 256) sw[i] = w[i];

    const int tc = tx & 15;
    const int gr = tx >> 4;
    const int c0 = tc * 4;
    const int rbase = blockIdx.x * 128 + gr * 8;

    int o[8];
    #pragma unroll
    for (int i = 0; i < 8; ++i) {
        int rg = rbase + i;
        o[i] = (rg < NN ? rg : 0) * IND;
    }
    __syncthreads();

    float4 bb = *(const float4*)&b[c0];
    float acc[8][4];
    #pragma unroll
    for (int i = 0; i < 8; ++i) {
        acc[i][0] = bb.x; acc[i][1] = bb.y; acc[i][2] = bb.z; acc[i][3] = bb.w;
    }

    #pragma unroll 1
    for (int kk = 0; kk < IND; kk += 4) {
        float4 a[8];
        #pragma unroll
        for (int i = 0; i < 8; ++i) a[i] = *(const float4*)(x + o[i] + kk);
        float4 b0 = *(const float4*)&sw[(kk + 0) * HID + c0];
        float4 b1 = *(const float4*)&sw[(kk + 1) * HID + c0];
        float4 b2 = *(const float4*)&sw[(kk + 2) * HID + c0];
        float4 b3 = *(const float4*)&sw[(kk + 3) * HID + c0];
        #pragma unroll
        for (int i = 0; i < 8; ++i) {
            acc[i][0] += a[i].x * b0.x + a[i].y * b1.x + a[i].z * b2.x + a[i].w * b3.x;
            acc[i][1] += a[i].x * b0.y + a[i].y * b1.y + a[i].z * b2.y + a[i].w * b3.y;
            acc[i][2] += a[i].x * b0.z + a[i].y * b1.z + a[i].z * b2.z + a[i].w * b3.z;
            acc[i][3] += a[i].x * b0.w + a[i].y * b1.w + a[i].z * b2.w + a[i].w * b3.w;
        }
    }

    #pragma unroll
    for (int i = 0; i < 8; ++i) {
        int rg = rbase + i;
        if (rg < NN)
            *(float4*)&h[rg * HID + c0] = make_float4(acc[i][0], acc[i][1], acc[i][2], acc[i][3]);
    }
}

// ---------------- conv transform: md = (hin @ W) * dinv  (64 -> 64) ---------

__global__ __launch_bounds__(256) void k_mm(const float* __restrict__ hin, const float* __restrict__ w,
                                            const float* __restrict__ dinv, float* __restrict__ md) {
    __shared__ float sw[HID * HID];     // 16 KB
    const int tx = threadIdx.x;
    for (int i = tx; i < HID * HID; i += 256) sw[i] = w[i];

    const int tc = tx & 15;
    const int gr = tx >> 4;
    const int c0 = tc * 4;
    const int rbase = blockIdx.x * 128 + gr * 8;

    int o[8];
    #pragma unroll
    for (int i = 0; i < 8; ++i) {
        int rg = rbase + i;
        o[i] = (rg < NN ? rg : 0) * HID;
    }
    __syncthreads();

    float acc[8][4] = {};

    #pragma unroll 1
    for (int kk = 0; kk < HID; kk += 4) {
        float4 a[8];
        #pragma unroll
        for (int i = 0; i < 8; ++i) a[i] = *(const float4*)(hin + o[i] + kk);
        float4 b0 = *(const float4*)&sw[(kk + 0) * HID + c0];
        float4 b1 = *(const float4*)&sw[(kk + 1) * HID + c0];
        float4 b2 = *(const float4*)&sw[(kk + 2) * HID + c0];
        float4 b3 = *(const float4*)&sw[(kk + 3) * HID + c0];
        #pragma unroll
        for (int i = 0; i < 8; ++i) {
            acc[i][0] += a[i].x * b0.x + a[i].y * b1.x + a[i].z * b2.x + a[i].w * b3.x;
            acc[i][1] += a[i].x * b0.y + a[i].y * b1.y + a[i].z * b2.y + a[i].w * b3.y;
            acc[i][2] += a[i].x * b0.z + a[i].y * b1.z + a[i].z * b2.z + a[i].w * b3.z;
            acc[i][3] += a[i].x * b0.w + a[i].y * b1.w + a[i].z * b2.w + a[i].w * b3.w;
        }
    }

    #pragma unroll
    for (int i = 0; i < 8; ++i) {
        int rg = rbase + i;
        if (rg < NN) {
            float di = dinv[rg];
            *(float4*)&md[rg * HID + c0] =
                make_float4(acc[i][0] * di, acc[i][1] * di, acc[i][2] * di, acc[i][3] * di);
        }
    }
}

// ---------------- bucket aggregate conv1: LDS-accumulated push --------------
// block = bucket; acc[128][64] in LDS; per edge: coalesced 256B md gather +
// conflict-free ds_add_f32 (lane i -> bank i%32, 2-way = free).

__global__ __launch_bounds__(256) void k_bagg(const float* __restrict__ md, const int* __restrict__ gcur,
                                              const int* __restrict__ ebuf, const float* __restrict__ dinv,
                                              const float* __restrict__ bias, float* __restrict__ hout) {
    __shared__ float acc[128][64];   // 32 KB
    const int tx = threadIdx.x;
    const int lane = tx & 63, wid = tx >> 6;
    const int b = blockIdx.x;

    for (int i = tx; i < 128 * 64; i += 256) ((float*)acc)[i] = 0.f;
    __syncthreads();

    const int cnt = gcur[b];
    const int* eb = ebuf + b * CAP;

    for (int e0 = wid * 64; e0 < cnt; e0 += 256) {
        int m = cnt - e0; if (m > 64) m = 64;
        int v = (lane < m) ? eb[e0 + lane] : 0;
        int j = 0;
        for (; j + 2 <= m; j += 2) {
            int v0 = __shfl(v, j, 64), v1 = __shfl(v, j + 1, 64);
            float a0 = md[(v0 >> 7) * HID + lane];
            float a1 = md[(v1 >> 7) * HID + lane];
            atomicAdd(&acc[v0 & 127][lane], a0);
            atomicAdd(&acc[v1 & 127][lane], a1);
        }
        for (; j < m; ++j) {
            int vj = __shfl(v, j, 64);
            atomicAdd(&acc[vj & 127][lane], md[(vj >> 7) * HID + lane]);
        }
    }
    __syncthreads();

    float bj = bias[lane];
    for (int n = wid; n < 128; n += 4) {
        int g = b * 128 + n;
        if (g < NN) {
            float val = dinv[g] * (acc[n][lane] + md[g * HID + lane]) + bj;
            hout[g * HID + lane] = val > 0.f ? val : 0.f;
        }
    }
}

// ---------------- bucket aggregate conv2 fused with scores ------------------

__global__ __launch_bounds__(256) void k_bagg2s(const float* __restrict__ md, const int* __restrict__ gcur,
        const int* __restrict__ ebuf, const float* __restrict__ dinv, const float* __restrict__ bias,
        const float* __restrict__ nw, const float* __restrict__ nb, const float* __restrict__ ew,
        float* __restrict__ out_node, float* __restrict__ ssrc, float* __restrict__ sdst) {
    __shared__ float acc[128][64];   // 32 KB
    const int tx = threadIdx.x;
    const int lane = tx & 63, wid = tx >> 6;
    const int b = blockIdx.x;

    for (int i = tx; i < 128 * 64; i += 256) ((float*)acc)[i] = 0.f;
    __syncthreads();

    const int cnt = gcur[b];
    const int* eb = ebuf + b * CAP;

    for (int e0 = wid * 64; e0 < cnt; e0 += 256) {
        int m = cnt - e0; if (m > 64) m = 64;
        int v = (lane < m) ? eb[e0 + lane] : 0;
        int j = 0;
        for (; j + 2 <= m; j += 2) {
            int v0 = __shfl(v, j, 64), v1 = __shfl(v, j + 1, 64);
            float a0 = md[(v0 >> 7) * HID + lane];
            float a1 = md[(v1 >> 7) * HID + lane];
            atomicAdd(&acc[v0 & 127][lane], a0);
            atomicAdd(&acc[v1 & 127][lane], a1);
        }
        for (; j < m; ++j) {
            int vj = __shfl(v, j, 64);
            atomicAdd(&acc[vj & 127][lane], md[(vj >> 7) * HID + lane]);
        }
    }
    __syncthreads();

    float bj = bias[lane];
    float w0 = nw[lane], w1 = ew[lane], w2 = ew[64 + lane];
    float nb0 = nb[0];
    for (int n = wid; n < 128; n += 4) {
        int g = b * 128 + n;
        if (g >= NN) continue;
        float v = dinv[g] * (acc[n][lane] + md[g * HID + lane]) + bj;
        v = v > 0.f ? v : 0.f;
        float a = v * w0, s1 = v * w1, s2 = v * w2;
        #pragma unroll
        for (int off = 32; off; off >>= 1) {
            a  += __shfl_xor(a,  off, 64);
            s1 += __shfl_xor(s1, off, 64);
            s2 += __shfl_xor(s2, off, 64);
        }
        if (lane == 0) {
            out_node[g] = 1.f / (1.f + expf(-(a + nb0)));
            ssrc[g] = s1;
            sdst[g] = s2;
        }
    }
}

// ---------------- edge scores ----------------

__global__ __launch_bounds__(256) void k_edge(const int* __restrict__ row, const int* __restrict__ col,
                                              const float* __restrict__ ssrc, const float* __restrict__ sdst,
                                              const float* __restrict__ eb, float* __restrict__ out_edge) {
    int stride = gridDim.x * 256;
    float eb0 = eb[0];
    for (int i = blockIdx.x * 256 + threadIdx.x; i < EE; i += stride) {
        float z = ssrc[row[i]] + sdst[col[i]] + eb0;
        out_edge[i] = 1.f / (1.f + expf(-z));
    }
}

extern "C" void kernel_launch(void* const* d_in, const int* in_sizes, int n_in,
                              void* d_out, int out_size, void* d_ws, size_t ws_size,
                              hipStream_t stream) {
    const float* x    = (const float*)d_in[0];
    const int*   ei   = (const int*)d_in[1];
    const float* fc_w = (const float*)d_in[2];
    const float* fc_b = (const float*)d_in[3];
    const float* c1w  = (const float*)d_in[4];
    const float* c1b  = (const float*)d_in[5];
    const float* c2w  = (const float*)d_in[6];
    const float* c2b  = (const float*)d_in[7];
    const float* nw   = (const float*)d_in[8];
    const float* nb   = (const float*)d_in[9];
    const float* ew   = (const float*)d_in[10];
    const float* eb   = (const float*)d_in[11];
    const int* row = ei;        // edge_index[0]
    const int* col = ei + EE;   // edge_index[1]

    // workspace layout (floats/ints, 4B each): total ~60.04 MB
    constexpr int NP = 102400;
    float* ws   = (float*)d_ws;
    float* dinv = ws;
    float* ssrc = ws + NP;
    float* sdst = ws + 2 * NP;
    int*   gcur = (int*)(ws + 3 * NP);            // NBUCK (pad 1024)
    int*   ebuf = (int*)(ws + 3 * NP + 1024);     // NBUCK*CAP ints
    float* A    = ws + 3 * NP + 1024 + NBUCK * CAP;   // h  [N*HID]
    float* B    = A + (size_t)NN * HID;               // md [N*HID]

    float* out_edge = (float*)d_out;
    float* out_node = out_edge + EE;

    const int nbG = (NN + 127) / 128;           // 782 GEMM tiles
    const int nbC = (EE + CHUNK - 1) / CHUNK;   // 391 multisplit chunks

    // ---- bucketize edges + degree norm ----
    k_zero    <<<(NBUCK + 255) / 256, 256, 0, stream>>>(gcur, NBUCK);
    k_bscatter<<<nbC, 256, 0, stream>>>(row, col, gcur, ebuf);
    k_deg     <<<NBUCK, 256, 0, stream>>>(gcur, ebuf, dinv);

    // ---- fc, conv1 transform, conv1 aggregate ----
    k_fc  <<<nbG, 256, 0, stream>>>(x, fc_w, fc_b, A);
    k_mm  <<<nbG, 256, 0, stream>>>(A, c1w, dinv, B);
    k_bagg<<<NBUCK, 256, 0, stream>>>(B, gcur, ebuf, dinv, c1b, A);

    // ---- conv2 transform + aggregate fused with scores ----
    k_mm    <<<nbG, 256, 0, stream>>>(A, c2w, dinv, B);
    k_bagg2s<<<NBUCK, 256, 0, stream>>>(B, gcur, ebuf, dinv, c2b,
                                        nw, nb, ew, out_node, ssrc, sdst);

    // ---- edge scores ----
    k_edge<<<2048, 256, 0, stream>>>(row, col, ssrc, sdst, eb, out_edge);
}

// Round 7
// 291.407 us; speedup vs baseline: 5.4223x; 5.4223x over previous
//
#include <hip/hip_runtime.h>
#include <math.h>

// Problem constants (from reference)
constexpr int NN  = 100000;   // nodes
constexpr int EE  = 1600000;  // edges
constexpr int IND = 128;      // input dim
constexpr int HID = 64;       // hidden dim

constexpr int NBUCK = (NN + 127) / 128;   // 782 buckets of 128 nodes
constexpr int CAP   = 2432;               // bucket capacity (passed at round 6: actual max < CAP)
constexpr int CHUNK = 4096;               // edges per multisplit block

// ---------------- small zero ----------------

__global__ __launch_bounds__(256) void k_zero(int* __restrict__ p, int n) {
    int i = blockIdx.x * 256 + threadIdx.x;
    if (i < n) p[i] = 0;
}

// ---------------- bucketized multisplit -------------------------------------
// Packs (row<<7)|(col&127) into bucket (col>>7)'s region of ebuf.
// Per-chunk LDS histogram -> 1 global atomic per non-empty bucket -> ranked
// writes (run-clustered, L2-hot tails; no partial-line write amplification).

__global__ __launch_bounds__(256) void k_bscatter(const int* __restrict__ row, const int* __restrict__ col,
                                                  int* __restrict__ gcur, int* __restrict__ ebuf) {
    __shared__ int lhist[NBUCK];
    __shared__ int lbase[NBUCK];
    __shared__ int lcur[NBUCK];
    const int tx = threadIdx.x;
    const int cbase = blockIdx.x * CHUNK;

    for (int b = tx; b < NBUCK; b += 256) lhist[b] = 0;
    __syncthreads();

    #pragma unroll
    for (int i = 0; i < CHUNK / 256; ++i) {
        int e = cbase + tx + i * 256;
        if (e < EE) atomicAdd(&lhist[col[e] >> 7], 1);
    }
    __syncthreads();

    for (int b = tx; b < NBUCK; b += 256) {
        int c = lhist[b];
        if (c) lbase[b] = atomicAdd(&gcur[b], c);
        lcur[b] = 0;
    }
    __syncthreads();

    #pragma unroll
    for (int i = 0; i < CHUNK / 256; ++i) {
        int e = cbase + tx + i * 256;
        if (e < EE) {
            int c = col[e];
            int b = c >> 7;
            int rank = atomicAdd(&lcur[b], 1);
            ebuf[b * CAP + lbase[b] + rank] = (row[e] << 7) | (c & 127);
        }
    }
}

// ---------------- in-place per-bucket node sort -----------------------------
// Loads the bucket's packed edges to LDS, histograms/scans the 128 local
// slots, writes rows back NODE-SORTED into the same ebuf region, and emits
// bc[g] = (local_base<<16)|cnt plus dinv[g]. ebuf becomes the prow array.

__global__ __launch_bounds__(256) void k_bsortip(const int* __restrict__ gcur, int* __restrict__ ebuf,
                                                 int* __restrict__ bc, float* __restrict__ dinv) {
    __shared__ int ebl[CAP];       // 9.7 KB
    __shared__ int h[128];
    __shared__ int sc[128];
    __shared__ int cur[128];
    const int tx = threadIdx.x;
    const int b = blockIdx.x;
    const int cnt = gcur[b];
    int* eb = ebuf + b * CAP;

    if (tx < 128) h[tx] = 0;
    for (int e = tx; e < cnt; e += 256) ebl[e] = eb[e];
    __syncthreads();
    for (int e = tx; e < cnt; e += 256) atomicAdd(&h[ebl[e] & 127], 1);
    __syncthreads();

    // inclusive Hillis-Steele scan over 128 slots
    if (tx < 128) sc[tx] = h[tx];
    __syncthreads();
    #pragma unroll
    for (int o = 1; o < 128; o <<= 1) {
        int add = (tx < 128 && tx >= o) ? sc[tx - o] : 0;
        __syncthreads();
        if (tx < 128) sc[tx] += add;
        __syncthreads();
    }
    if (tx < 128) {
        int ex = sc[tx] - h[tx];       // exclusive base within bucket
        cur[tx] = ex;
        int g = b * 128 + tx;
        if (g < NN) {
            bc[g]   = (ex << 16) | h[tx];
            dinv[g] = rsqrtf((float)(h[tx] + 1));   // +1 = self-loop
        }
    }
    __syncthreads();

    for (int e = tx; e < cnt; e += 256) {
        int v = ebl[e];
        int r = atomicAdd(&cur[v & 127], 1);
        eb[r] = v >> 7;                // node-sorted row index
    }
}

// ---------------- fc: h = x @ fc_w + fc_b  (128 -> 64) ----------------------
// A streamed from global (duplicate lane addresses coalesce); B in LDS;
// #pragma unroll 1 bounds VGPR (round-4 spill lesson).

__global__ __launch_bounds__(256) void k_fc(const float* __restrict__ x, const float* __restrict__ w,
                                            const float* __restrict__ b, float* __restrict__ h) {
    __shared__ float sw[IND * HID];     // 32 KB  [k][c]
    const int tx = threadIdx.x;
    for (int i = tx; i < IND * HID; i += 256) sw[i] = w[i];

    const int tc = tx & 15;
    const int gr = tx >> 4;
    const int c0 = tc * 4;
    const int rbase = blockIdx.x * 128 + gr * 8;

    int o[8];
    #pragma unroll
    for (int i = 0; i < 8; ++i) {
        int rg = rbase + i;
        o[i] = (rg < NN ? rg : 0) * IND;
    }
    __syncthreads();

    float4 bb = *(const float4*)&b[c0];
    float acc[8][4];
    #pragma unroll
    for (int i = 0; i < 8; ++i) {
        acc[i][0] = bb.x; acc[i][1] = bb.y; acc[i][2] = bb.z; acc[i][3] = bb.w;
    }

    #pragma unroll 1
    for (int kk = 0; kk < IND; kk += 4) {
        float4 a[8];
        #pragma unroll
        for (int i = 0; i < 8; ++i) a[i] = *(const float4*)(x + o[i] + kk);
        float4 b0 = *(const float4*)&sw[(kk + 0) * HID + c0];
        float4 b1 = *(const float4*)&sw[(kk + 1) * HID + c0];
        float4 b2 = *(const float4*)&sw[(kk + 2) * HID + c0];
        float4 b3 = *(const float4*)&sw[(kk + 3) * HID + c0];
        #pragma unroll
        for (int i = 0; i < 8; ++i) {
            acc[i][0] += a[i].x * b0.x + a[i].y * b1.x + a[i].z * b2.x + a[i].w * b3.x;
            acc[i][1] += a[i].x * b0.y + a[i].y * b1.y + a[i].z * b2.y + a[i].w * b3.y;
            acc[i][2] += a[i].x * b0.z + a[i].y * b1.z + a[i].z * b2.z + a[i].w * b3.z;
            acc[i][3] += a[i].x * b0.w + a[i].y * b1.w + a[i].z * b2.w + a[i].w * b3.w;
        }
    }

    #pragma unroll
    for (int i = 0; i < 8; ++i) {
        int rg = rbase + i;
        if (rg < NN)
            *(float4*)&h[rg * HID + c0] = make_float4(acc[i][0], acc[i][1], acc[i][2], acc[i][3]);
    }
}

// ---------------- conv transform: md = (hin @ W) * dinv  (64 -> 64) ---------

__global__ __launch_bounds__(256) void k_mm(const float* __restrict__ hin, const float* __restrict__ w,
                                            const float* __restrict__ dinv, float* __restrict__ md) {
    __shared__ float sw[HID * HID];     // 16 KB
    const int tx = threadIdx.x;
    for (int i = tx; i < HID * HID; i += 256) sw[i] = w[i];

    const int tc = tx & 15;
    const int gr = tx >> 4;
    const int c0 = tc * 4;
    const int rbase = blockIdx.x * 128 + gr * 8;

    int o[8];
    #pragma unroll
    for (int i = 0; i < 8; ++i) {
        int rg = rbase + i;
        o[i] = (rg < NN ? rg : 0) * HID;
    }
    __syncthreads();

    float acc[8][4] = {};

    #pragma unroll 1
    for (int kk = 0; kk < HID; kk += 4) {
        float4 a[8];
        #pragma unroll
        for (int i = 0; i < 8; ++i) a[i] = *(const float4*)(hin + o[i] + kk);
        float4 b0 = *(const float4*)&sw[(kk + 0) * HID + c0];
        float4 b1 = *(const float4*)&sw[(kk + 1) * HID + c0];
        float4 b2 = *(const float4*)&sw[(kk + 2) * HID + c0];
        float4 b3 = *(const float4*)&sw[(kk + 3) * HID + c0];
        #pragma unroll
        for (int i = 0; i < 8; ++i) {
            acc[i][0] += a[i].x * b0.x + a[i].y * b1.x + a[i].z * b2.x + a[i].w * b3.x;
            acc[i][1] += a[i].x * b0.y + a[i].y * b1.y + a[i].z * b2.y + a[i].w * b3.y;
            acc[i][2] += a[i].x * b0.z + a[i].y * b1.z + a[i].z * b2.z + a[i].w * b3.z;
            acc[i][3] += a[i].x * b0.w + a[i].y * b1.w + a[i].z * b2.w + a[i].w * b3.w;
        }
    }

    #pragma unroll
    for (int i = 0; i < 8; ++i) {
        int rg = rbase + i;
        if (rg < NN) {
            float di = dinv[rg];
            *(float4*)&md[rg * HID + c0] =
                make_float4(acc[i][0] * di, acc[i][1] * di, acc[i][2] * di, acc[i][3] * di);
        }
    }
}

// ---------------- gather conv1: h1 = relu(dinv*(self + sum md[r]) + b) ------
// wave per node; lane = feature; CSR pull from node-sorted ebuf.

__global__ __launch_bounds__(256) void k_gather(const float* __restrict__ md, const int* __restrict__ prow,
                                                const int* __restrict__ bc, const float* __restrict__ dinv,
                                                const float* __restrict__ b, float* __restrict__ hout) {
    int lane = threadIdx.x & 63;
    int wid  = (blockIdx.x * blockDim.x + threadIdx.x) >> 6;
    int nwv  = (gridDim.x * blockDim.x) >> 6;
    float bj = b[lane];
    for (int i = wid; i < NN; i += nwv) {
        int v = bc[i];
        int s = (i >> 7) * CAP + (v >> 16);
        int n = v & 0xFFFF;
        float acc = md[i * HID + lane];
        int e = 0;
        for (; e + 4 <= n; e += 4) {
            int r0 = prow[s + e],     r1 = prow[s + e + 1];
            int r2 = prow[s + e + 2], r3 = prow[s + e + 3];
            float v0 = md[r0 * HID + lane], v1 = md[r1 * HID + lane];
            float v2 = md[r2 * HID + lane], v3 = md[r3 * HID + lane];
            acc += (v0 + v1) + (v2 + v3);
        }
        for (; e < n; ++e) acc += md[prow[s + e] * HID + lane];
        float val = dinv[i] * acc + bj;
        hout[i * HID + lane] = val > 0.f ? val : 0.f;
    }
}

// ---------------- gather conv2 fused with scores ----------------------------

__global__ __launch_bounds__(256) void k_gather2s(const float* __restrict__ md, const int* __restrict__ prow,
        const int* __restrict__ bc, const float* __restrict__ dinv, const float* __restrict__ b,
        const float* __restrict__ nw, const float* __restrict__ nb, const float* __restrict__ ew,
        float* __restrict__ out_node, float* __restrict__ ssrc, float* __restrict__ sdst) {
    int lane = threadIdx.x & 63;
    int wid  = (blockIdx.x * blockDim.x + threadIdx.x) >> 6;
    int nwv  = (gridDim.x * blockDim.x) >> 6;
    float bj = b[lane];
    float w0 = nw[lane], w1 = ew[lane], w2 = ew[64 + lane];
    float nb0 = nb[0];
    for (int i = wid; i < NN; i += nwv) {
        int vv = bc[i];
        int s = (i >> 7) * CAP + (vv >> 16);
        int n = vv & 0xFFFF;
        float acc = md[i * HID + lane];
        int e = 0;
        for (; e + 4 <= n; e += 4) {
            int r0 = prow[s + e],     r1 = prow[s + e + 1];
            int r2 = prow[s + e + 2], r3 = prow[s + e + 3];
            float v0 = md[r0 * HID + lane], v1 = md[r1 * HID + lane];
            float v2 = md[r2 * HID + lane], v3 = md[r3 * HID + lane];
            acc += (v0 + v1) + (v2 + v3);
        }
        for (; e < n; ++e) acc += md[prow[s + e] * HID + lane];
        float v = dinv[i] * acc + bj;
        v = v > 0.f ? v : 0.f;
        float a = v * w0, s1 = v * w1, s2 = v * w2;
        #pragma unroll
        for (int off = 32; off; off >>= 1) {
            a  += __shfl_xor(a,  off, 64);
            s1 += __shfl_xor(s1, off, 64);
            s2 += __shfl_xor(s2, off, 64);
        }
        if (lane == 0) {
            out_node[i] = 1.f / (1.f + expf(-(a + nb0)));
            ssrc[i] = s1;
            sdst[i] = s2;
        }
    }
}

// ---------------- edge scores ----------------

__global__ __launch_bounds__(256) void k_edge(const int* __restrict__ row, const int* __restrict__ col,
                                              const float* __restrict__ ssrc, const float* __restrict__ sdst,
                                              const float* __restrict__ eb, float* __restrict__ out_edge) {
    int stride = gridDim.x * 256;
    float eb0 = eb[0];
    for (int i = blockIdx.x * 256 + threadIdx.x; i < EE; i += stride) {
        float z = ssrc[row[i]] + sdst[col[i]] + eb0;
        out_edge[i] = 1.f / (1.f + expf(-z));
    }
}

extern "C" void kernel_launch(void* const* d_in, const int* in_sizes, int n_in,
                              void* d_out, int out_size, void* d_ws, size_t ws_size,
                              hipStream_t stream) {
    const float* x    = (const float*)d_in[0];
    const int*   ei   = (const int*)d_in[1];
    const float* fc_w = (const float*)d_in[2];
    const float* fc_b = (const float*)d_in[3];
    const float* c1w  = (const float*)d_in[4];
    const float* c1b  = (const float*)d_in[5];
    const float* c2w  = (const float*)d_in[6];
    const float* c2b  = (const float*)d_in[7];
    const float* nw   = (const float*)d_in[8];
    const float* nb   = (const float*)d_in[9];
    const float* ew   = (const float*)d_in[10];
    const float* eb   = (const float*)d_in[11];
    const int* row = ei;        // edge_index[0]
    const int* col = ei + EE;   // edge_index[1]

    // workspace layout (4B elems): total ~59.6 MB
    constexpr int NP = 100352;                      // 392*256 >= NN
    float* ws   = (float*)d_ws;
    float* dinv = ws;                               // NP
    int*   bc   = (int*)(ws + NP);                  // NP  (base<<16 | cnt)
    int*   gcur = (int*)(ws + 2 * NP);              // 1024
    int*   ebuf = (int*)(ws + 2 * NP + 1024);       // NBUCK*CAP
    float* A    = ws + 2 * NP + 1024 + NBUCK * CAP; // h1 [N*HID]
    float* B    = A + (size_t)NN * HID;             // md [N*HID]
    float* ssrc = A;                                // alias: A dead after 2nd k_mm
    float* sdst = A + NP;

    float* out_edge = (float*)d_out;
    float* out_node = out_edge + EE;

    const int nbG = (NN + 127) / 128;           // 782 GEMM tiles
    const int nbC = (EE + CHUNK - 1) / CHUNK;   // 391 multisplit chunks

    // ---- bucketize + in-place node sort (builds CSR + dinv) ----
    k_zero    <<<(NBUCK + 255) / 256, 256, 0, stream>>>(gcur, NBUCK);
    k_bscatter<<<nbC, 256, 0, stream>>>(row, col, gcur, ebuf);
    k_bsortip <<<NBUCK, 256, 0, stream>>>(gcur, ebuf, bc, dinv);

    // ---- fc, conv1 transform, conv1 gather ----
    k_fc    <<<nbG, 256, 0, stream>>>(x, fc_w, fc_b, A);
    k_mm    <<<nbG, 256, 0, stream>>>(A, c1w, dinv, B);
    k_gather<<<2048, 256, 0, stream>>>(B, ebuf, bc, dinv, c1b, A);

    // ---- conv2 transform + gather fused with scores ----
    k_mm      <<<nbG, 256, 0, stream>>>(A, c2w, dinv, B);
    k_gather2s<<<2048, 256, 0, stream>>>(B, ebuf, bc, dinv, c2b,
                                         nw, nb, ew, out_node, ssrc, sdst);

    // ---- edge scores ----
    k_edge<<<2048, 256, 0, stream>>>(row, col, ssrc, sdst, eb, out_edge);
}

// Round 8
// 254.773 us; speedup vs baseline: 6.2020x; 1.1438x over previous
//
#include <hip/hip_runtime.h>
#include <math.h>

// Problem constants (from reference)
constexpr int NN  = 100000;   // nodes
constexpr int EE  = 1600000;  // edges
constexpr int IND = 128;      // input dim
constexpr int HID = 64;       // hidden dim

constexpr int NBUCK = (NN + 127) / 128;   // 782 buckets of 128 nodes
constexpr int CAP   = 2432;               // bucket capacity (validated in rounds 6/7)
constexpr int CHUNK = 4096;               // edges per multisplit block

// bf16 helpers (round-to-nearest-even)
__device__ __forceinline__ unsigned short f2bf(float f) {
    union { float f; unsigned int u; } v; v.f = f;
    unsigned int r = (v.u + 0x7FFFu + ((v.u >> 16) & 1u)) >> 16;
    return (unsigned short)r;
}
__device__ __forceinline__ float bf2f(unsigned short h) {
    union { unsigned int u; float f; } v; v.u = ((unsigned int)h) << 16;
    return v.f;
}

// ---------------- small zero ----------------

__global__ __launch_bounds__(256) void k_zero(int* __restrict__ p, int n) {
    int i = blockIdx.x * 256 + threadIdx.x;
    if (i < n) p[i] = 0;
}

// ---------------- bucketized multisplit -------------------------------------

__global__ __launch_bounds__(256) void k_bscatter(const int* __restrict__ row, const int* __restrict__ col,
                                                  int* __restrict__ gcur, int* __restrict__ ebuf) {
    __shared__ int lhist[NBUCK];
    __shared__ int lbase[NBUCK];
    __shared__ int lcur[NBUCK];
    const int tx = threadIdx.x;
    const int cbase = blockIdx.x * CHUNK;

    for (int b = tx; b < NBUCK; b += 256) lhist[b] = 0;
    __syncthreads();

    #pragma unroll
    for (int i = 0; i < CHUNK / 256; ++i) {
        int e = cbase + tx + i * 256;
        if (e < EE) atomicAdd(&lhist[col[e] >> 7], 1);
    }
    __syncthreads();

    for (int b = tx; b < NBUCK; b += 256) {
        int c = lhist[b];
        if (c) lbase[b] = atomicAdd(&gcur[b], c);
        lcur[b] = 0;
    }
    __syncthreads();

    #pragma unroll
    for (int i = 0; i < CHUNK / 256; ++i) {
        int e = cbase + tx + i * 256;
        if (e < EE) {
            int c = col[e];
            int b = c >> 7;
            int rank = atomicAdd(&lcur[b], 1);
            ebuf[b * CAP + lbase[b] + rank] = (row[e] << 7) | (c & 127);
        }
    }
}

// ---------------- in-place per-bucket node sort -----------------------------

__global__ __launch_bounds__(256) void k_bsortip(const int* __restrict__ gcur, int* __restrict__ ebuf,
                                                 int* __restrict__ bc, float* __restrict__ dinv) {
    __shared__ int ebl[CAP];
    __shared__ int h[128];
    __shared__ int sc[128];
    __shared__ int cur[128];
    const int tx = threadIdx.x;
    const int b = blockIdx.x;
    const int cnt = gcur[b];
    int* eb = ebuf + b * CAP;

    if (tx < 128) h[tx] = 0;
    for (int e = tx; e < cnt; e += 256) ebl[e] = eb[e];
    __syncthreads();
    for (int e = tx; e < cnt; e += 256) atomicAdd(&h[ebl[e] & 127], 1);
    __syncthreads();

    if (tx < 128) sc[tx] = h[tx];
    __syncthreads();
    #pragma unroll
    for (int o = 1; o < 128; o <<= 1) {
        int add = (tx < 128 && tx >= o) ? sc[tx - o] : 0;
        __syncthreads();
        if (tx < 128) sc[tx] += add;
        __syncthreads();
    }
    if (tx < 128) {
        int ex = sc[tx] - h[tx];
        cur[tx] = ex;
        int g = b * 128 + tx;
        if (g < NN) {
            bc[g]   = (ex << 16) | h[tx];
            dinv[g] = rsqrtf((float)(h[tx] + 1));   // +1 = self-loop
        }
    }
    __syncthreads();

    for (int e = tx; e < cnt; e += 256) {
        int v = ebl[e];
        int r = atomicAdd(&cur[v & 127], 1);
        eb[r] = v >> 7;
    }
}

// ---------------- fc: h = x @ fc_w + fc_b  (128 -> 64) ----------------------

__global__ __launch_bounds__(256) void k_fc(const float* __restrict__ x, const float* __restrict__ w,
                                            const float* __restrict__ b, float* __restrict__ h) {
    __shared__ float sw[IND * HID];     // 32 KB
    const int tx = threadIdx.x;
    for (int i = tx; i < IND * HID; i += 256) sw[i] = w[i];

    const int tc = tx & 15;
    const int gr = tx >> 4;
    const int c0 = tc * 4;
    const int rbase = blockIdx.x * 128 + gr * 8;

    int o[8];
    #pragma unroll
    for (int i = 0; i < 8; ++i) {
        int rg = rbase + i;
        o[i] = (rg < NN ? rg : 0) * IND;
    }
    __syncthreads();

    float4 bb = *(const float4*)&b[c0];
    float acc[8][4];
    #pragma unroll
    for (int i = 0; i < 8; ++i) {
        acc[i][0] = bb.x; acc[i][1] = bb.y; acc[i][2] = bb.z; acc[i][3] = bb.w;
    }

    #pragma unroll 1
    for (int kk = 0; kk < IND; kk += 4) {
        float4 a[8];
        #pragma unroll
        for (int i = 0; i < 8; ++i) a[i] = *(const float4*)(x + o[i] + kk);
        float4 b0 = *(const float4*)&sw[(kk + 0) * HID + c0];
        float4 b1 = *(const float4*)&sw[(kk + 1) * HID + c0];
        float4 b2 = *(const float4*)&sw[(kk + 2) * HID + c0];
        float4 b3 = *(const float4*)&sw[(kk + 3) * HID + c0];
        #pragma unroll
        for (int i = 0; i < 8; ++i) {
            acc[i][0] += a[i].x * b0.x + a[i].y * b1.x + a[i].z * b2.x + a[i].w * b3.x;
            acc[i][1] += a[i].x * b0.y + a[i].y * b1.y + a[i].z * b2.y + a[i].w * b3.y;
            acc[i][2] += a[i].x * b0.z + a[i].y * b1.z + a[i].z * b2.z + a[i].w * b3.z;
            acc[i][3] += a[i].x * b0.w + a[i].y * b1.w + a[i].z * b2.w + a[i].w * b3.w;
        }
    }

    #pragma unroll
    for (int i = 0; i < 8; ++i) {
        int rg = rbase + i;
        if (rg < NN)
            *(float4*)&h[rg * HID + c0] = make_float4(acc[i][0], acc[i][1], acc[i][2], acc[i][3]);
    }
}

// ---------------- conv transform: mdb = bf16((hin @ W) * dinv) --------------

__global__ __launch_bounds__(256) void k_mm(const float* __restrict__ hin, const float* __restrict__ w,
                                            const float* __restrict__ dinv,
                                            unsigned short* __restrict__ mdb) {
    __shared__ float sw[HID * HID];     // 16 KB
    const int tx = threadIdx.x;
    for (int i = tx; i < HID * HID; i += 256) sw[i] = w[i];

    const int tc = tx & 15;
    const int gr = tx >> 4;
    const int c0 = tc * 4;
    const int rbase = blockIdx.x * 128 + gr * 8;

    int o[8];
    #pragma unroll
    for (int i = 0; i < 8; ++i) {
        int rg = rbase + i;
        o[i] = (rg < NN ? rg : 0) * HID;
    }
    __syncthreads();

    float acc[8][4] = {};

    #pragma unroll 1
    for (int kk = 0; kk < HID; kk += 4) {
        float4 a[8];
        #pragma unroll
        for (int i = 0; i < 8; ++i) a[i] = *(const float4*)(hin + o[i] + kk);
        float4 b0 = *(const float4*)&sw[(kk + 0) * HID + c0];
        float4 b1 = *(const float4*)&sw[(kk + 1) * HID + c0];
        float4 b2 = *(const float4*)&sw[(kk + 2) * HID + c0];
        float4 b3 = *(const float4*)&sw[(kk + 3) * HID + c0];
        #pragma unroll
        for (int i = 0; i < 8; ++i) {
            acc[i][0] += a[i].x * b0.x + a[i].y * b1.x + a[i].z * b2.x + a[i].w * b3.x;
            acc[i][1] += a[i].x * b0.y + a[i].y * b1.y + a[i].z * b2.y + a[i].w * b3.y;
            acc[i][2] += a[i].x * b0.z + a[i].y * b1.z + a[i].z * b2.z + a[i].w * b3.z;
            acc[i][3] += a[i].x * b0.w + a[i].y * b1.w + a[i].z * b2.w + a[i].w * b3.w;
        }
    }

    #pragma unroll
    for (int i = 0; i < 8; ++i) {
        int rg = rbase + i;
        if (rg < NN) {
            float di = dinv[rg];
            ushort4 o4;
            o4.x = f2bf(acc[i][0] * di); o4.y = f2bf(acc[i][1] * di);
            o4.z = f2bf(acc[i][2] * di); o4.w = f2bf(acc[i][3] * di);
            *(ushort4*)&mdb[rg * HID + c0] = o4;
        }
    }
}

// ---------------- gather conv1 (bf16 payload): h1 = relu(...) ---------------
// wave per node; lane = feature; 8 rows in flight (128B lines x 8).

__global__ __launch_bounds__(256) void k_gather(const unsigned short* __restrict__ mdb,
                                                const int* __restrict__ prow, const int* __restrict__ bc,
                                                const float* __restrict__ dinv, const float* __restrict__ b,
                                                float* __restrict__ hout) {
    int lane = threadIdx.x & 63;
    int wid  = (blockIdx.x * blockDim.x + threadIdx.x) >> 6;
    int nwv  = (gridDim.x * blockDim.x) >> 6;
    float bj = b[lane];
    for (int i = wid; i < NN; i += nwv) {
        int v = bc[i];
        int s = (i >> 7) * CAP + (v >> 16);
        int n = v & 0xFFFF;
        float acc = bf2f(mdb[i * HID + lane]);   // self-loop term
        int e = 0;
        for (; e + 8 <= n; e += 8) {
            int r0 = prow[s + e],     r1 = prow[s + e + 1];
            int r2 = prow[s + e + 2], r3 = prow[s + e + 3];
            int r4 = prow[s + e + 4], r5 = prow[s + e + 5];
            int r6 = prow[s + e + 6], r7 = prow[s + e + 7];
            float v0 = bf2f(mdb[r0 * HID + lane]), v1 = bf2f(mdb[r1 * HID + lane]);
            float v2 = bf2f(mdb[r2 * HID + lane]), v3 = bf2f(mdb[r3 * HID + lane]);
            float v4 = bf2f(mdb[r4 * HID + lane]), v5 = bf2f(mdb[r5 * HID + lane]);
            float v6 = bf2f(mdb[r6 * HID + lane]), v7 = bf2f(mdb[r7 * HID + lane]);
            acc += ((v0 + v1) + (v2 + v3)) + ((v4 + v5) + (v6 + v7));
        }
        for (; e + 4 <= n; e += 4) {
            int r0 = prow[s + e],     r1 = prow[s + e + 1];
            int r2 = prow[s + e + 2], r3 = prow[s + e + 3];
            float v0 = bf2f(mdb[r0 * HID + lane]), v1 = bf2f(mdb[r1 * HID + lane]);
            float v2 = bf2f(mdb[r2 * HID + lane]), v3 = bf2f(mdb[r3 * HID + lane]);
            acc += (v0 + v1) + (v2 + v3);
        }
        for (; e < n; ++e) acc += bf2f(mdb[prow[s + e] * HID + lane]);
        float val = dinv[i] * acc + bj;
        hout[i * HID + lane] = val > 0.f ? val : 0.f;
    }
}

// ---------------- gather conv2 fused with scores (bf16 payload) -------------

__global__ __launch_bounds__(256) void k_gather2s(const unsigned short* __restrict__ mdb,
        const int* __restrict__ prow, const int* __restrict__ bc, const float* __restrict__ dinv,
        const float* __restrict__ b, const float* __restrict__ nw, const float* __restrict__ nb,
        const float* __restrict__ ew, float* __restrict__ out_node,
        float* __restrict__ ssrc, float* __restrict__ sdst) {
    int lane = threadIdx.x & 63;
    int wid  = (blockIdx.x * blockDim.x + threadIdx.x) >> 6;
    int nwv  = (gridDim.x * blockDim.x) >> 6;
    float bj = b[lane];
    float w0 = nw[lane], w1 = ew[lane], w2 = ew[64 + lane];
    float nb0 = nb[0];
    for (int i = wid; i < NN; i += nwv) {
        int vv = bc[i];
        int s = (i >> 7) * CAP + (vv >> 16);
        int n = vv & 0xFFFF;
        float acc = bf2f(mdb[i * HID + lane]);
        int e = 0;
        for (; e + 8 <= n; e += 8) {
            int r0 = prow[s + e],     r1 = prow[s + e + 1];
            int r2 = prow[s + e + 2], r3 = prow[s + e + 3];
            int r4 = prow[s + e + 4], r5 = prow[s + e + 5];
            int r6 = prow[s + e + 6], r7 = prow[s + e + 7];
            float v0 = bf2f(mdb[r0 * HID + lane]), v1 = bf2f(mdb[r1 * HID + lane]);
            float v2 = bf2f(mdb[r2 * HID + lane]), v3 = bf2f(mdb[r3 * HID + lane]);
            float v4 = bf2f(mdb[r4 * HID + lane]), v5 = bf2f(mdb[r5 * HID + lane]);
            float v6 = bf2f(mdb[r6 * HID + lane]), v7 = bf2f(mdb[r7 * HID + lane]);
            acc += ((v0 + v1) + (v2 + v3)) + ((v4 + v5) + (v6 + v7));
        }
        for (; e + 4 <= n; e += 4) {
            int r0 = prow[s + e],     r1 = prow[s + e + 1];
            int r2 = prow[s + e + 2], r3 = prow[s + e + 3];
            float v0 = bf2f(mdb[r0 * HID + lane]), v1 = bf2f(mdb[r1 * HID + lane]);
            float v2 = bf2f(mdb[r2 * HID + lane]), v3 = bf2f(mdb[r3 * HID + lane]);
            acc += (v0 + v1) + (v2 + v3);
        }
        for (; e < n; ++e) acc += bf2f(mdb[prow[s + e] * HID + lane]);
        float v = dinv[i] * acc + bj;
        v = v > 0.f ? v : 0.f;
        float a = v * w0, s1 = v * w1, s2 = v * w2;
        #pragma unroll
        for (int off = 32; off; off >>= 1) {
            a  += __shfl_xor(a,  off, 64);
            s1 += __shfl_xor(s1, off, 64);
            s2 += __shfl_xor(s2, off, 64);
        }
        if (lane == 0) {
            out_node[i] = 1.f / (1.f + expf(-(a + nb0)));
            ssrc[i] = s1;
            sdst[i] = s2;
        }
    }
}

// ---------------- edge scores ----------------

__global__ __launch_bounds__(256) void k_edge(const int* __restrict__ row, const int* __restrict__ col,
                                              const float* __restrict__ ssrc, const float* __restrict__ sdst,
                                              const float* __restrict__ eb, float* __restrict__ out_edge) {
    int stride = gridDim.x * 256;
    float eb0 = eb[0];
    for (int i = blockIdx.x * 256 + threadIdx.x; i < EE; i += stride) {
        float z = ssrc[row[i]] + sdst[col[i]] + eb0;
        out_edge[i] = 1.f / (1.f + expf(-z));
    }
}

extern "C" void kernel_launch(void* const* d_in, const int* in_sizes, int n_in,
                              void* d_out, int out_size, void* d_ws, size_t ws_size,
                              hipStream_t stream) {
    const float* x    = (const float*)d_in[0];
    const int*   ei   = (const int*)d_in[1];
    const float* fc_w = (const float*)d_in[2];
    const float* fc_b = (const float*)d_in[3];
    const float* c1w  = (const float*)d_in[4];
    const float* c1b  = (const float*)d_in[5];
    const float* c2w  = (const float*)d_in[6];
    const float* c2b  = (const float*)d_in[7];
    const float* nw   = (const float*)d_in[8];
    const float* nb   = (const float*)d_in[9];
    const float* ew   = (const float*)d_in[10];
    const float* eb   = (const float*)d_in[11];
    const int* row = ei;        // edge_index[0]
    const int* col = ei + EE;   // edge_index[1]

    // workspace layout (4B units): ~47 MB total
    constexpr int NP = 100352;
    float* ws   = (float*)d_ws;
    float* dinv = ws;                               // NP
    int*   bc   = (int*)(ws + NP);                  // NP
    int*   gcur = (int*)(ws + 2 * NP);              // 1024
    int*   ebuf = (int*)(ws + 2 * NP + 1024);       // NBUCK*CAP
    float* A    = ws + 2 * NP + 1024 + NBUCK * CAP; // h [N*HID] f32
    unsigned short* Bbf = (unsigned short*)(A + (size_t)NN * HID);  // md bf16 [N*HID]
    float* ssrc = A;                                // alias: A dead after 2nd k_mm
    float* sdst = A + NP;

    float* out_edge = (float*)d_out;
    float* out_node = out_edge + EE;

    const int nbG = (NN + 127) / 128;           // 782 GEMM tiles
    const int nbC = (EE + CHUNK - 1) / CHUNK;   // 391 multisplit chunks

    // ---- bucketize + in-place node sort (builds CSR + dinv) ----
    k_zero    <<<(NBUCK + 255) / 256, 256, 0, stream>>>(gcur, NBUCK);
    k_bscatter<<<nbC, 256, 0, stream>>>(row, col, gcur, ebuf);
    k_bsortip <<<NBUCK, 256, 0, stream>>>(gcur, ebuf, bc, dinv);

    // ---- fc, conv1 transform, conv1 gather ----
    k_fc    <<<nbG, 256, 0, stream>>>(x, fc_w, fc_b, A);
    k_mm    <<<nbG, 256, 0, stream>>>(A, c1w, dinv, Bbf);
    k_gather<<<2048, 256, 0, stream>>>(Bbf, ebuf, bc, dinv, c1b, A);

    // ---- conv2 transform + gather fused with scores ----
    k_mm      <<<nbG, 256, 0, stream>>>(A, c2w, dinv, Bbf);
    k_gather2s<<<2048, 256, 0, stream>>>(Bbf, ebuf, bc, dinv, c2b,
                                         nw, nb, ew, out_node, ssrc, sdst);

    // ---- edge scores ----
    k_edge<<<2048, 256, 0, stream>>>(row, col, ssrc, sdst, eb, out_edge);
}

// Round 9
// 241.206 us; speedup vs baseline: 6.5508x; 1.0562x over previous
//
#include <hip/hip_runtime.h>
#include <math.h>

// Problem constants (from reference)
constexpr int NN  = 100000;   // nodes
constexpr int EE  = 1600000;  // edges
constexpr int IND = 128;      // input dim
constexpr int HID = 64;       // hidden dim

constexpr int NBUCK = (NN + 127) / 128;   // 782 buckets of 128 nodes
constexpr int CAP   = 2432;               // bucket capacity (validated rounds 6-8)
constexpr int CHUNK = 4096;               // edges per multisplit block

// bf16 helpers
__device__ __forceinline__ unsigned short f2bf(float f) {
    union { float f; unsigned int u; } v; v.f = f;
    unsigned int r = (v.u + 0x7FFFu + ((v.u >> 16) & 1u)) >> 16;
    return (unsigned short)r;
}
// unpack a uint holding two bf16 (lo = bits 0..15, hi = bits 16..31)
__device__ __forceinline__ void unp(unsigned int u, float& lo, float& hi) {
    union { unsigned int x; float f; } a, c;
    a.x = u << 16; c.x = u & 0xFFFF0000u;
    lo = a.f; hi = c.f;
}

// ---------------- small zero ----------------

__global__ __launch_bounds__(256) void k_zero(int* __restrict__ p, int n) {
    int i = blockIdx.x * 256 + threadIdx.x;
    if (i < n) p[i] = 0;
}

// ---------------- bucketized multisplit -------------------------------------

__global__ __launch_bounds__(256) void k_bscatter(const int* __restrict__ row, const int* __restrict__ col,
                                                  int* __restrict__ gcur, int* __restrict__ ebuf) {
    __shared__ int lhist[NBUCK];
    __shared__ int lbase[NBUCK];
    __shared__ int lcur[NBUCK];
    const int tx = threadIdx.x;
    const int cbase = blockIdx.x * CHUNK;

    for (int b = tx; b < NBUCK; b += 256) lhist[b] = 0;
    __syncthreads();

    #pragma unroll
    for (int i = 0; i < CHUNK / 256; ++i) {
        int e = cbase + tx + i * 256;
        if (e < EE) atomicAdd(&lhist[col[e] >> 7], 1);
    }
    __syncthreads();

    for (int b = tx; b < NBUCK; b += 256) {
        int c = lhist[b];
        if (c) lbase[b] = atomicAdd(&gcur[b], c);
        lcur[b] = 0;
    }
    __syncthreads();

    #pragma unroll
    for (int i = 0; i < CHUNK / 256; ++i) {
        int e = cbase + tx + i * 256;
        if (e < EE) {
            int c = col[e];
            int b = c >> 7;
            int rank = atomicAdd(&lcur[b], 1);
            ebuf[b * CAP + lbase[b] + rank] = (row[e] << 7) | (c & 127);
        }
    }
}

// ---------------- in-place per-bucket node sort -----------------------------

__global__ __launch_bounds__(256) void k_bsortip(const int* __restrict__ gcur, int* __restrict__ ebuf,
                                                 int* __restrict__ bc, float* __restrict__ dinv) {
    __shared__ int ebl[CAP];
    __shared__ int h[128];
    __shared__ int sc[128];
    __shared__ int cur[128];
    const int tx = threadIdx.x;
    const int b = blockIdx.x;
    const int cnt = gcur[b];
    int* eb = ebuf + b * CAP;

    if (tx < 128) h[tx] = 0;
    for (int e = tx; e < cnt; e += 256) ebl[e] = eb[e];
    __syncthreads();
    for (int e = tx; e < cnt; e += 256) atomicAdd(&h[ebl[e] & 127], 1);
    __syncthreads();

    if (tx < 128) sc[tx] = h[tx];
    __syncthreads();
    #pragma unroll
    for (int o = 1; o < 128; o <<= 1) {
        int add = (tx < 128 && tx >= o) ? sc[tx - o] : 0;
        __syncthreads();
        if (tx < 128) sc[tx] += add;
        __syncthreads();
    }
    if (tx < 128) {
        int ex = sc[tx] - h[tx];
        cur[tx] = ex;
        int g = b * 128 + tx;
        if (g < NN) {
            bc[g]   = (ex << 16) | h[tx];
            dinv[g] = rsqrtf((float)(h[tx] + 1));   // +1 = self-loop
        }
    }
    __syncthreads();

    for (int e = tx; e < cnt; e += 256) {
        int v = ebl[e];
        int r = atomicAdd(&cur[v & 127], 1);
        eb[r] = v >> 7;
    }
}

// ---------------- fc: h = x @ fc_w + fc_b  (128 -> 64) ----------------------

__global__ __launch_bounds__(256) void k_fc(const float* __restrict__ x, const float* __restrict__ w,
                                            const float* __restrict__ b, float* __restrict__ h) {
    __shared__ float sw[IND * HID];     // 32 KB
    const int tx = threadIdx.x;
    for (int i = tx; i < IND * HID; i += 256) sw[i] = w[i];

    const int tc = tx & 15;
    const int gr = tx >> 4;
    const int c0 = tc * 4;
    const int rbase = blockIdx.x * 128 + gr * 8;

    int o[8];
    #pragma unroll
    for (int i = 0; i < 8; ++i) {
        int rg = rbase + i;
        o[i] = (rg < NN ? rg : 0) * IND;
    }
    __syncthreads();

    float4 bb = *(const float4*)&b[c0];
    float acc[8][4];
    #pragma unroll
    for (int i = 0; i < 8; ++i) {
        acc[i][0] = bb.x; acc[i][1] = bb.y; acc[i][2] = bb.z; acc[i][3] = bb.w;
    }

    #pragma unroll 1
    for (int kk = 0; kk < IND; kk += 4) {
        float4 a[8];
        #pragma unroll
        for (int i = 0; i < 8; ++i) a[i] = *(const float4*)(x + o[i] + kk);
        float4 b0 = *(const float4*)&sw[(kk + 0) * HID + c0];
        float4 b1 = *(const float4*)&sw[(kk + 1) * HID + c0];
        float4 b2 = *(const float4*)&sw[(kk + 2) * HID + c0];
        float4 b3 = *(const float4*)&sw[(kk + 3) * HID + c0];
        #pragma unroll
        for (int i = 0; i < 8; ++i) {
            acc[i][0] += a[i].x * b0.x + a[i].y * b1.x + a[i].z * b2.x + a[i].w * b3.x;
            acc[i][1] += a[i].x * b0.y + a[i].y * b1.y + a[i].z * b2.y + a[i].w * b3.y;
            acc[i][2] += a[i].x * b0.z + a[i].y * b1.z + a[i].z * b2.z + a[i].w * b3.z;
            acc[i][3] += a[i].x * b0.w + a[i].y * b1.w + a[i].z * b2.w + a[i].w * b3.w;
        }
    }

    #pragma unroll
    for (int i = 0; i < 8; ++i) {
        int rg = rbase + i;
        if (rg < NN)
            *(float4*)&h[rg * HID + c0] = make_float4(acc[i][0], acc[i][1], acc[i][2], acc[i][3]);
    }
}

// ---------------- conv transform: mdb = bf16((hin @ W) * dinv) --------------

__global__ __launch_bounds__(256) void k_mm(const float* __restrict__ hin, const float* __restrict__ w,
                                            const float* __restrict__ dinv,
                                            unsigned short* __restrict__ mdb) {
    __shared__ float sw[HID * HID];     // 16 KB
    const int tx = threadIdx.x;
    for (int i = tx; i < HID * HID; i += 256) sw[i] = w[i];

    const int tc = tx & 15;
    const int gr = tx >> 4;
    const int c0 = tc * 4;
    const int rbase = blockIdx.x * 128 + gr * 8;

    int o[8];
    #pragma unroll
    for (int i = 0; i < 8; ++i) {
        int rg = rbase + i;
        o[i] = (rg < NN ? rg : 0) * HID;
    }
    __syncthreads();

    float acc[8][4] = {};

    #pragma unroll 1
    for (int kk = 0; kk < HID; kk += 4) {
        float4 a[8];
        #pragma unroll
        for (int i = 0; i < 8; ++i) a[i] = *(const float4*)(hin + o[i] + kk);
        float4 b0 = *(const float4*)&sw[(kk + 0) * HID + c0];
        float4 b1 = *(const float4*)&sw[(kk + 1) * HID + c0];
        float4 b2 = *(const float4*)&sw[(kk + 2) * HID + c0];
        float4 b3 = *(const float4*)&sw[(kk + 3) * HID + c0];
        #pragma unroll
        for (int i = 0; i < 8; ++i) {
            acc[i][0] += a[i].x * b0.x + a[i].y * b1.x + a[i].z * b2.x + a[i].w * b3.x;
            acc[i][1] += a[i].x * b0.y + a[i].y * b1.y + a[i].z * b2.y + a[i].w * b3.y;
            acc[i][2] += a[i].x * b0.z + a[i].y * b1.z + a[i].z * b2.z + a[i].w * b3.z;
            acc[i][3] += a[i].x * b0.w + a[i].y * b1.w + a[i].z * b2.w + a[i].w * b3.w;
        }
    }

    #pragma unroll
    for (int i = 0; i < 8; ++i) {
        int rg = rbase + i;
        if (rg < NN) {
            float di = dinv[rg];
            ushort4 o4;
            o4.x = f2bf(acc[i][0] * di); o4.y = f2bf(acc[i][1] * di);
            o4.z = f2bf(acc[i][2] * di); o4.w = f2bf(acc[i][3] * di);
            *(ushort4*)&mdb[rg * HID + c0] = o4;
        }
    }
}

// ---------------- gather conv1 (packed): wave = node, lane = (q, f4) --------
// q = lane>>4 selects edge slot (4 edges/pass); f4 = lane&15 selects a
// 4-feature quad loaded as one uint2 (4 bf16). Quarter partial sums merged
// with shfl_xor(32), shfl_xor(16). 4x fewer VMEM instrs, ~1.6x fewer VALU.

__global__ __launch_bounds__(256) void k_gather(const unsigned short* __restrict__ mdb,
                                                const int* __restrict__ prow, const int* __restrict__ bc,
                                                const float* __restrict__ dinv, const float* __restrict__ b,
                                                float* __restrict__ hout) {
    const uint2* mdq = (const uint2*)mdb;      // 4 bf16 per element
    int lane = threadIdx.x & 63;
    int q    = lane >> 4;
    int f4   = lane & 15;
    int wid  = (blockIdx.x * blockDim.x + threadIdx.x) >> 6;
    int nwv  = (gridDim.x * blockDim.x) >> 6;
    float4 bj = *(const float4*)&b[f4 * 4];

    for (int i = wid; i < NN; i += nwv) {
        int vv = bc[i];
        int s = (i >> 7) * CAP + (vv >> 16);
        int n = vv & 0xFFFF;
        float a0 = 0.f, a1 = 0.f, a2 = 0.f, a3 = 0.f;
        if (q == 0) {                      // self-loop term, counted once
            uint2 u = mdq[i * 16 + f4];
            float l, h_;
            unp(u.x, l, h_); a0 += l; a1 += h_;
            unp(u.y, l, h_); a2 += l; a3 += h_;
        }
        int e = 0;
        for (; e + 8 <= n; e += 8) {       // 8 edges per iteration, unguarded
            int r0 = prow[s + e + q];
            int r1 = prow[s + e + 4 + q];
            uint2 u0 = mdq[r0 * 16 + f4];
            uint2 u1 = mdq[r1 * 16 + f4];
            float l, h_;
            unp(u0.x, l, h_); a0 += l; a1 += h_;
            unp(u0.y, l, h_); a2 += l; a3 += h_;
            unp(u1.x, l, h_); a0 += l; a1 += h_;
            unp(u1.y, l, h_); a2 += l; a3 += h_;
        }
        for (; e < n; e += 4) {            // guarded tail (<= 2 iterations)
            int ej = e + q;
            int r = prow[s + (ej < n ? ej : 0)];
            uint2 u = mdq[r * 16 + f4];
            if (ej < n) {
                float l, h_;
                unp(u.x, l, h_); a0 += l; a1 += h_;
                unp(u.y, l, h_); a2 += l; a3 += h_;
            }
        }
        // merge quarters
        a0 += __shfl_xor(a0, 32, 64); a1 += __shfl_xor(a1, 32, 64);
        a2 += __shfl_xor(a2, 32, 64); a3 += __shfl_xor(a3, 32, 64);
        a0 += __shfl_xor(a0, 16, 64); a1 += __shfl_xor(a1, 16, 64);
        a2 += __shfl_xor(a2, 16, 64); a3 += __shfl_xor(a3, 16, 64);

        float di = dinv[i];
        float4 o;
        o.x = fmaxf(di * a0 + bj.x, 0.f);
        o.y = fmaxf(di * a1 + bj.y, 0.f);
        o.z = fmaxf(di * a2 + bj.z, 0.f);
        o.w = fmaxf(di * a3 + bj.w, 0.f);
        if (q == 0) *(float4*)&hout[i * HID + f4 * 4] = o;
    }
}

// ---------------- gather conv2 fused with scores (packed) -------------------

__global__ __launch_bounds__(256) void k_gather2s(const unsigned short* __restrict__ mdb,
        const int* __restrict__ prow, const int* __restrict__ bc, const float* __restrict__ dinv,
        const float* __restrict__ b, const float* __restrict__ nw, const float* __restrict__ nb,
        const float* __restrict__ ew, float* __restrict__ out_node,
        float* __restrict__ ssrc, float* __restrict__ sdst) {
    const uint2* mdq = (const uint2*)mdb;
    int lane = threadIdx.x & 63;
    int q    = lane >> 4;
    int f4   = lane & 15;
    int wid  = (blockIdx.x * blockDim.x + threadIdx.x) >> 6;
    int nwv  = (gridDim.x * blockDim.x) >> 6;
    float4 bj  = *(const float4*)&b[f4 * 4];
    float4 wn  = *(const float4*)&nw[f4 * 4];
    float4 we1 = *(const float4*)&ew[f4 * 4];
    float4 we2 = *(const float4*)&ew[64 + f4 * 4];
    float nb0 = nb[0];

    for (int i = wid; i < NN; i += nwv) {
        int vv = bc[i];
        int s = (i >> 7) * CAP + (vv >> 16);
        int n = vv & 0xFFFF;
        float a0 = 0.f, a1 = 0.f, a2 = 0.f, a3 = 0.f;
        if (q == 0) {
            uint2 u = mdq[i * 16 + f4];
            float l, h_;
            unp(u.x, l, h_); a0 += l; a1 += h_;
            unp(u.y, l, h_); a2 += l; a3 += h_;
        }
        int e = 0;
        for (; e + 8 <= n; e += 8) {
            int r0 = prow[s + e + q];
            int r1 = prow[s + e + 4 + q];
            uint2 u0 = mdq[r0 * 16 + f4];
            uint2 u1 = mdq[r1 * 16 + f4];
            float l, h_;
            unp(u0.x, l, h_); a0 += l; a1 += h_;
            unp(u0.y, l, h_); a2 += l; a3 += h_;
            unp(u1.x, l, h_); a0 += l; a1 += h_;
            unp(u1.y, l, h_); a2 += l; a3 += h_;
        }
        for (; e < n; e += 4) {
            int ej = e + q;
            int r = prow[s + (ej < n ? ej : 0)];
            uint2 u = mdq[r * 16 + f4];
            if (ej < n) {
                float l, h_;
                unp(u.x, l, h_); a0 += l; a1 += h_;
                unp(u.y, l, h_); a2 += l; a3 += h_;
            }
        }
        a0 += __shfl_xor(a0, 32, 64); a1 += __shfl_xor(a1, 32, 64);
        a2 += __shfl_xor(a2, 32, 64); a3 += __shfl_xor(a3, 32, 64);
        a0 += __shfl_xor(a0, 16, 64); a1 += __shfl_xor(a1, 16, 64);
        a2 += __shfl_xor(a2, 16, 64); a3 += __shfl_xor(a3, 16, 64);

        float di = dinv[i];
        float v0 = fmaxf(di * a0 + bj.x, 0.f);
        float v1 = fmaxf(di * a1 + bj.y, 0.f);
        float v2 = fmaxf(di * a2 + bj.z, 0.f);
        float v3 = fmaxf(di * a3 + bj.w, 0.f);

        float a  = v0 * wn.x  + v1 * wn.y  + v2 * wn.z  + v3 * wn.w;
        float s1 = v0 * we1.x + v1 * we1.y + v2 * we1.z + v3 * we1.w;
        float s2 = v0 * we2.x + v1 * we2.y + v2 * we2.z + v3 * we2.w;
        #pragma unroll
        for (int off = 8; off; off >>= 1) {
            a  += __shfl_xor(a,  off, 64);
            s1 += __shfl_xor(s1, off, 64);
            s2 += __shfl_xor(s2, off, 64);
        }
        if (lane == 0) {
            out_node[i] = 1.f / (1.f + expf(-(a + nb0)));
            ssrc[i] = s1;
            sdst[i] = s2;
        }
    }
}

// ---------------- edge scores (x4 vectorized) -------------------------------

__global__ __launch_bounds__(256) void k_edge(const int4* __restrict__ row4, const int4* __restrict__ col4,
                                              const float* __restrict__ ssrc, const float* __restrict__ sdst,
                                              const float* __restrict__ eb, float4* __restrict__ out4) {
    constexpr int NQ = EE / 4;
    int i = blockIdx.x * 256 + threadIdx.x;
    if (i >= NQ) return;
    float eb0 = eb[0];
    int4 r = row4[i], c = col4[i];
    float4 o;
    float z;
    z = ssrc[r.x] + sdst[c.x] + eb0; o.x = 1.f / (1.f + expf(-z));
    z = ssrc[r.y] + sdst[c.y] + eb0; o.y = 1.f / (1.f + expf(-z));
    z = ssrc[r.z] + sdst[c.z] + eb0; o.z = 1.f / (1.f + expf(-z));
    z = ssrc[r.w] + sdst[c.w] + eb0; o.w = 1.f / (1.f + expf(-z));
    out4[i] = o;
}

extern "C" void kernel_launch(void* const* d_in, const int* in_sizes, int n_in,
                              void* d_out, int out_size, void* d_ws, size_t ws_size,
                              hipStream_t stream) {
    const float* x    = (const float*)d_in[0];
    const int*   ei   = (const int*)d_in[1];
    const float* fc_w = (const float*)d_in[2];
    const float* fc_b = (const float*)d_in[3];
    const float* c1w  = (const float*)d_in[4];
    const float* c1b  = (const float*)d_in[5];
    const float* c2w  = (const float*)d_in[6];
    const float* c2b  = (const float*)d_in[7];
    const float* nw   = (const float*)d_in[8];
    const float* nb   = (const float*)d_in[9];
    const float* ew   = (const float*)d_in[10];
    const float* eb   = (const float*)d_in[11];
    const int* row = ei;        // edge_index[0]
    const int* col = ei + EE;   // edge_index[1]

    // workspace layout (4B units): ~47 MB total
    constexpr int NP = 100352;
    float* ws   = (float*)d_ws;
    float* dinv = ws;                               // NP
    int*   bc   = (int*)(ws + NP);                  // NP
    int*   gcur = (int*)(ws + 2 * NP);              // 1024
    int*   ebuf = (int*)(ws + 2 * NP + 1024);       // NBUCK*CAP (even count)
    float* A    = ws + 2 * NP + 1024 + NBUCK * CAP; // h [N*HID] f32
    unsigned short* Bbf = (unsigned short*)(A + (size_t)NN * HID);  // md bf16 (8B-aligned)
    float* ssrc = A;                                // alias: A dead after 2nd k_mm
    float* sdst = A + NP;

    float* out_edge = (float*)d_out;
    float* out_node = out_edge + EE;

    const int nbG = (NN + 127) / 128;           // 782 GEMM tiles
    const int nbC = (EE + CHUNK - 1) / CHUNK;   // 391 multisplit chunks
    const int nbQ = (EE / 4 + 255) / 256;       // 1563 edge-quad blocks

    // ---- bucketize + in-place node sort (builds CSR + dinv) ----
    k_zero    <<<(NBUCK + 255) / 256, 256, 0, stream>>>(gcur, NBUCK);
    k_bscatter<<<nbC, 256, 0, stream>>>(row, col, gcur, ebuf);
    k_bsortip <<<NBUCK, 256, 0, stream>>>(gcur, ebuf, bc, dinv);

    // ---- fc, conv1 transform, conv1 gather ----
    k_fc    <<<nbG, 256, 0, stream>>>(x, fc_w, fc_b, A);
    k_mm    <<<nbG, 256, 0, stream>>>(A, c1w, dinv, Bbf);
    k_gather<<<2048, 256, 0, stream>>>(Bbf, ebuf, bc, dinv, c1b, A);

    // ---- conv2 transform + gather fused with scores ----
    k_mm      <<<nbG, 256, 0, stream>>>(A, c2w, dinv, Bbf);
    k_gather2s<<<2048, 256, 0, stream>>>(Bbf, ebuf, bc, dinv, c2b,
                                         nw, nb, ew, out_node, ssrc, sdst);

    // ---- edge scores ----
    k_edge<<<nbQ, 256, 0, stream>>>((const int4*)row, (const int4*)col,
                                    ssrc, sdst, eb, (float4*)out_edge);
}

// Round 10
// 236.926 us; speedup vs baseline: 6.6692x; 1.0181x over previous
//
#include <hip/hip_runtime.h>
#include <math.h>

// Problem constants (from reference)
constexpr int NN  = 100000;   // nodes
constexpr int EE  = 1600000;  // edges
constexpr int IND = 128;      // input dim
constexpr int HID = 64;       // hidden dim

constexpr int NBUCK = (NN + 127) / 128;   // 782 buckets of 128 nodes
constexpr int CAP   = 2432;               // bucket capacity (validated rounds 6-9)
constexpr int CHUNK = 4096;               // edges per multisplit block

// bf16 helpers
__device__ __forceinline__ unsigned short f2bf(float f) {
    union { float f; unsigned int u; } v; v.f = f;
    unsigned int r = (v.u + 0x7FFFu + ((v.u >> 16) & 1u)) >> 16;
    return (unsigned short)r;
}
// unpack a uint holding two bf16 (lo = bits 0..15, hi = bits 16..31)
__device__ __forceinline__ void unp(unsigned int u, float& lo, float& hi) {
    union { unsigned int x; float f; } a, c;
    a.x = u << 16; c.x = u & 0xFFFF0000u;
    lo = a.f; hi = c.f;
}

// ---------------- small zero ----------------

__global__ __launch_bounds__(256) void k_zero(int* __restrict__ p, int n) {
    int i = blockIdx.x * 256 + threadIdx.x;
    if (i < n) p[i] = 0;
}

// ---------------- bucketized multisplit -------------------------------------

__global__ __launch_bounds__(256) void k_bscatter(const int* __restrict__ row, const int* __restrict__ col,
                                                  int* __restrict__ gcur, int* __restrict__ ebuf) {
    __shared__ int lhist[NBUCK];
    __shared__ int lbase[NBUCK];
    __shared__ int lcur[NBUCK];
    const int tx = threadIdx.x;
    const int cbase = blockIdx.x * CHUNK;

    for (int b = tx; b < NBUCK; b += 256) lhist[b] = 0;
    __syncthreads();

    #pragma unroll
    for (int i = 0; i < CHUNK / 256; ++i) {
        int e = cbase + tx + i * 256;
        if (e < EE) atomicAdd(&lhist[col[e] >> 7], 1);
    }
    __syncthreads();

    for (int b = tx; b < NBUCK; b += 256) {
        int c = lhist[b];
        if (c) lbase[b] = atomicAdd(&gcur[b], c);
        lcur[b] = 0;
    }
    __syncthreads();

    #pragma unroll
    for (int i = 0; i < CHUNK / 256; ++i) {
        int e = cbase + tx + i * 256;
        if (e < EE) {
            int c = col[e];
            int b = c >> 7;
            int rank = atomicAdd(&lcur[b], 1);
            ebuf[b * CAP + lbase[b] + rank] = (row[e] << 7) | (c & 127);
        }
    }
}

// ---------------- in-place per-bucket node sort -----------------------------

__global__ __launch_bounds__(256) void k_bsortip(const int* __restrict__ gcur, int* __restrict__ ebuf,
                                                 int* __restrict__ bc, float* __restrict__ dinv) {
    __shared__ int ebl[CAP];
    __shared__ int h[128];
    __shared__ int sc[128];
    __shared__ int cur[128];
    const int tx = threadIdx.x;
    const int b = blockIdx.x;
    const int cnt = gcur[b];
    int* eb = ebuf + b * CAP;

    if (tx < 128) h[tx] = 0;
    for (int e = tx; e < cnt; e += 256) ebl[e] = eb[e];
    __syncthreads();
    for (int e = tx; e < cnt; e += 256) atomicAdd(&h[ebl[e] & 127], 1);
    __syncthreads();

    if (tx < 128) sc[tx] = h[tx];
    __syncthreads();
    #pragma unroll
    for (int o = 1; o < 128; o <<= 1) {
        int add = (tx < 128 && tx >= o) ? sc[tx - o] : 0;
        __syncthreads();
        if (tx < 128) sc[tx] += add;
        __syncthreads();
    }
    if (tx < 128) {
        int ex = sc[tx] - h[tx];
        cur[tx] = ex;
        int g = b * 128 + tx;
        if (g < NN) {
            bc[g]   = (ex << 16) | h[tx];
            dinv[g] = rsqrtf((float)(h[tx] + 1));   // +1 = self-loop
        }
    }
    __syncthreads();

    for (int e = tx; e < cnt; e += 256) {
        int v = ebl[e];
        int r = atomicAdd(&cur[v & 127], 1);
        eb[r] = v >> 7;
    }
}

// ---------------- fc: h = x @ fc_w + fc_b  (128 -> 64) ----------------------
// 64-row x 64-col tile, 1563 blocks (6/CU; LDS caps at 5 -> ~20 waves/CU).
// 4x4 per thread, K-loop unroll 2 (8 A-loads in flight, VGPR ~90 no spill).

__global__ __launch_bounds__(256) void k_fc(const float* __restrict__ x, const float* __restrict__ w,
                                            const float* __restrict__ b, float* __restrict__ h) {
    __shared__ float sw[IND * HID];     // 32 KB
    const int tx = threadIdx.x;
    for (int i = tx; i < IND * HID; i += 256) sw[i] = w[i];

    const int tc = tx & 15;
    const int gr = tx >> 4;
    const int c0 = tc * 4;
    const int rbase = blockIdx.x * 64 + gr * 4;

    int o[4];
    #pragma unroll
    for (int i = 0; i < 4; ++i) {
        int rg = rbase + i;
        o[i] = (rg < NN ? rg : 0) * IND;
    }
    __syncthreads();

    float4 bb = *(const float4*)&b[c0];
    float acc[4][4];
    #pragma unroll
    for (int i = 0; i < 4; ++i) {
        acc[i][0] = bb.x; acc[i][1] = bb.y; acc[i][2] = bb.z; acc[i][3] = bb.w;
    }

    #pragma unroll 2
    for (int kk = 0; kk < IND; kk += 4) {
        float4 a[4];
        #pragma unroll
        for (int i = 0; i < 4; ++i) a[i] = *(const float4*)(x + o[i] + kk);
        float4 b0 = *(const float4*)&sw[(kk + 0) * HID + c0];
        float4 b1 = *(const float4*)&sw[(kk + 1) * HID + c0];
        float4 b2 = *(const float4*)&sw[(kk + 2) * HID + c0];
        float4 b3 = *(const float4*)&sw[(kk + 3) * HID + c0];
        #pragma unroll
        for (int i = 0; i < 4; ++i) {
            acc[i][0] += a[i].x * b0.x + a[i].y * b1.x + a[i].z * b2.x + a[i].w * b3.x;
            acc[i][1] += a[i].x * b0.y + a[i].y * b1.y + a[i].z * b2.y + a[i].w * b3.y;
            acc[i][2] += a[i].x * b0.z + a[i].y * b1.z + a[i].z * b2.z + a[i].w * b3.z;
            acc[i][3] += a[i].x * b0.w + a[i].y * b1.w + a[i].z * b2.w + a[i].w * b3.w;
        }
    }

    #pragma unroll
    for (int i = 0; i < 4; ++i) {
        int rg = rbase + i;
        if (rg < NN)
            *(float4*)&h[rg * HID + c0] = make_float4(acc[i][0], acc[i][1], acc[i][2], acc[i][3]);
    }
}

// ---------------- conv transform: mdb = bf16((hin @ W) * dinv) --------------
// 64-row tiles, 1563 blocks, 16 KB LDS (~6 blocks/CU), unroll 2.

__global__ __launch_bounds__(256) void k_mm(const float* __restrict__ hin, const float* __restrict__ w,
                                            const float* __restrict__ dinv,
                                            unsigned short* __restrict__ mdb) {
    __shared__ float sw[HID * HID];     // 16 KB
    const int tx = threadIdx.x;
    for (int i = tx; i < HID * HID; i += 256) sw[i] = w[i];

    const int tc = tx & 15;
    const int gr = tx >> 4;
    const int c0 = tc * 4;
    const int rbase = blockIdx.x * 64 + gr * 4;

    int o[4];
    #pragma unroll
    for (int i = 0; i < 4; ++i) {
        int rg = rbase + i;
        o[i] = (rg < NN ? rg : 0) * HID;
    }
    __syncthreads();

    float acc[4][4] = {};

    #pragma unroll 2
    for (int kk = 0; kk < HID; kk += 4) {
        float4 a[4];
        #pragma unroll
        for (int i = 0; i < 4; ++i) a[i] = *(const float4*)(hin + o[i] + kk);
        float4 b0 = *(const float4*)&sw[(kk + 0) * HID + c0];
        float4 b1 = *(const float4*)&sw[(kk + 1) * HID + c0];
        float4 b2 = *(const float4*)&sw[(kk + 2) * HID + c0];
        float4 b3 = *(const float4*)&sw[(kk + 3) * HID + c0];
        #pragma unroll
        for (int i = 0; i < 4; ++i) {
            acc[i][0] += a[i].x * b0.x + a[i].y * b1.x + a[i].z * b2.x + a[i].w * b3.x;
            acc[i][1] += a[i].x * b0.y + a[i].y * b1.y + a[i].z * b2.y + a[i].w * b3.y;
            acc[i][2] += a[i].x * b0.z + a[i].y * b1.z + a[i].z * b2.z + a[i].w * b3.z;
            acc[i][3] += a[i].x * b0.w + a[i].y * b1.w + a[i].z * b2.w + a[i].w * b3.w;
        }
    }

    #pragma unroll
    for (int i = 0; i < 4; ++i) {
        int rg = rbase + i;
        if (rg < NN) {
            float di = dinv[rg];
            ushort4 o4;
            o4.x = f2bf(acc[i][0] * di); o4.y = f2bf(acc[i][1] * di);
            o4.z = f2bf(acc[i][2] * di); o4.w = f2bf(acc[i][3] * di);
            *(ushort4*)&mdb[rg * HID + c0] = o4;
        }
    }
}

// ---------------- gather conv1 (packed): wave = node, lane = (q, f4) --------

__global__ __launch_bounds__(256) void k_gather(const unsigned short* __restrict__ mdb,
                                                const int* __restrict__ prow, const int* __restrict__ bc,
                                                const float* __restrict__ dinv, const float* __restrict__ b,
                                                float* __restrict__ hout) {
    const uint2* mdq = (const uint2*)mdb;      // 4 bf16 per element
    int lane = threadIdx.x & 63;
    int q    = lane >> 4;
    int f4   = lane & 15;
    int wid  = (blockIdx.x * blockDim.x + threadIdx.x) >> 6;
    int nwv  = (gridDim.x * blockDim.x) >> 6;
    float4 bj = *(const float4*)&b[f4 * 4];

    for (int i = wid; i < NN; i += nwv) {
        int vv = bc[i];
        int s = (i >> 7) * CAP + (vv >> 16);
        int n = vv & 0xFFFF;
        float a0 = 0.f, a1 = 0.f, a2 = 0.f, a3 = 0.f;
        if (q == 0) {                      // self-loop term, counted once
            uint2 u = mdq[i * 16 + f4];
            float l, h_;
            unp(u.x, l, h_); a0 += l; a1 += h_;
            unp(u.y, l, h_); a2 += l; a3 += h_;
        }
        int e = 0;
        for (; e + 8 <= n; e += 8) {       // 8 edges per iteration, unguarded
            int r0 = prow[s + e + q];
            int r1 = prow[s + e + 4 + q];
            uint2 u0 = mdq[r0 * 16 + f4];
            uint2 u1 = mdq[r1 * 16 + f4];
            float l, h_;
            unp(u0.x, l, h_); a0 += l; a1 += h_;
            unp(u0.y, l, h_); a2 += l; a3 += h_;
            unp(u1.x, l, h_); a0 += l; a1 += h_;
            unp(u1.y, l, h_); a2 += l; a3 += h_;
        }
        for (; e < n; e += 4) {            // guarded tail (<= 2 iterations)
            int ej = e + q;
            int r = prow[s + (ej < n ? ej : 0)];
            uint2 u = mdq[r * 16 + f4];
            if (ej < n) {
                float l, h_;
                unp(u.x, l, h_); a0 += l; a1 += h_;
                unp(u.y, l, h_); a2 += l; a3 += h_;
            }
        }
        // merge quarters
        a0 += __shfl_xor(a0, 32, 64); a1 += __shfl_xor(a1, 32, 64);
        a2 += __shfl_xor(a2, 32, 64); a3 += __shfl_xor(a3, 32, 64);
        a0 += __shfl_xor(a0, 16, 64); a1 += __shfl_xor(a1, 16, 64);
        a2 += __shfl_xor(a2, 16, 64); a3 += __shfl_xor(a3, 16, 64);

        float di = dinv[i];
        float4 o;
        o.x = fmaxf(di * a0 + bj.x, 0.f);
        o.y = fmaxf(di * a1 + bj.y, 0.f);
        o.z = fmaxf(di * a2 + bj.z, 0.f);
        o.w = fmaxf(di * a3 + bj.w, 0.f);
        if (q == 0) *(float4*)&hout[i * HID + f4 * 4] = o;
    }
}

// ---------------- gather conv2 fused with scores (packed) -------------------

__global__ __launch_bounds__(256) void k_gather2s(const unsigned short* __restrict__ mdb,
        const int* __restrict__ prow, const int* __restrict__ bc, const float* __restrict__ dinv,
        const float* __restrict__ b, const float* __restrict__ nw, const float* __restrict__ nb,
        const float* __restrict__ ew, float* __restrict__ out_node,
        float* __restrict__ ssrc, float* __restrict__ sdst) {
    const uint2* mdq = (const uint2*)mdb;
    int lane = threadIdx.x & 63;
    int q    = lane >> 4;
    int f4   = lane & 15;
    int wid  = (blockIdx.x * blockDim.x + threadIdx.x) >> 6;
    int nwv  = (gridDim.x * blockDim.x) >> 6;
    float4 bj  = *(const float4*)&b[f4 * 4];
    float4 wn  = *(const float4*)&nw[f4 * 4];
    float4 we1 = *(const float4*)&ew[f4 * 4];
    float4 we2 = *(const float4*)&ew[64 + f4 * 4];
    float nb0 = nb[0];

    for (int i = wid; i < NN; i += nwv) {
        int vv = bc[i];
        int s = (i >> 7) * CAP + (vv >> 16);
        int n = vv & 0xFFFF;
        float a0 = 0.f, a1 = 0.f, a2 = 0.f, a3 = 0.f;
        if (q == 0) {
            uint2 u = mdq[i * 16 + f4];
            float l, h_;
            unp(u.x, l, h_); a0 += l; a1 += h_;
            unp(u.y, l, h_); a2 += l; a3 += h_;
        }
        int e = 0;
        for (; e + 8 <= n; e += 8) {
            int r0 = prow[s + e + q];
            int r1 = prow[s + e + 4 + q];
            uint2 u0 = mdq[r0 * 16 + f4];
            uint2 u1 = mdq[r1 * 16 + f4];
            float l, h_;
            unp(u0.x, l, h_); a0 += l; a1 += h_;
            unp(u0.y, l, h_); a2 += l; a3 += h_;
            unp(u1.x, l, h_); a0 += l; a1 += h_;
            unp(u1.y, l, h_); a2 += l; a3 += h_;
        }
        for (; e < n; e += 4) {
            int ej = e + q;
            int r = prow[s + (ej < n ? ej : 0)];
            uint2 u = mdq[r * 16 + f4];
            if (ej < n) {
                float l, h_;
                unp(u.x, l, h_); a0 += l; a1 += h_;
                unp(u.y, l, h_); a2 += l; a3 += h_;
            }
        }
        a0 += __shfl_xor(a0, 32, 64); a1 += __shfl_xor(a1, 32, 64);
        a2 += __shfl_xor(a2, 32, 64); a3 += __shfl_xor(a3, 32, 64);
        a0 += __shfl_xor(a0, 16, 64); a1 += __shfl_xor(a1, 16, 64);
        a2 += __shfl_xor(a2, 16, 64); a3 += __shfl_xor(a3, 16, 64);

        float di = dinv[i];
        float v0 = fmaxf(di * a0 + bj.x, 0.f);
        float v1 = fmaxf(di * a1 + bj.y, 0.f);
        float v2 = fmaxf(di * a2 + bj.z, 0.f);
        float v3 = fmaxf(di * a3 + bj.w, 0.f);

        float a  = v0 * wn.x  + v1 * wn.y  + v2 * wn.z  + v3 * wn.w;
        float s1 = v0 * we1.x + v1 * we1.y + v2 * we1.z + v3 * we1.w;
        float s2 = v0 * we2.x + v1 * we2.y + v2 * we2.z + v3 * we2.w;
        #pragma unroll
        for (int off = 8; off; off >>= 1) {
            a  += __shfl_xor(a,  off, 64);
            s1 += __shfl_xor(s1, off, 64);
            s2 += __shfl_xor(s2, off, 64);
        }
        if (lane == 0) {
            out_node[i] = 1.f / (1.f + expf(-(a + nb0)));
            ssrc[i] = s1;
            sdst[i] = s2;
        }
    }
}

// ---------------- edge scores (x4 vectorized) -------------------------------

__global__ __launch_bounds__(256) void k_edge(const int4* __restrict__ row4, const int4* __restrict__ col4,
                                              const float* __restrict__ ssrc, const float* __restrict__ sdst,
                                              const float* __restrict__ eb, float4* __restrict__ out4) {
    constexpr int NQ = EE / 4;
    int i = blockIdx.x * 256 + threadIdx.x;
    if (i >= NQ) return;
    float eb0 = eb[0];
    int4 r = row4[i], c = col4[i];
    float4 o;
    float z;
    z = ssrc[r.x] + sdst[c.x] + eb0; o.x = 1.f / (1.f + expf(-z));
    z = ssrc[r.y] + sdst[c.y] + eb0; o.y = 1.f / (1.f + expf(-z));
    z = ssrc[r.z] + sdst[c.z] + eb0; o.z = 1.f / (1.f + expf(-z));
    z = ssrc[r.w] + sdst[c.w] + eb0; o.w = 1.f / (1.f + expf(-z));
    out4[i] = o;
}

extern "C" void kernel_launch(void* const* d_in, const int* in_sizes, int n_in,
                              void* d_out, int out_size, void* d_ws, size_t ws_size,
                              hipStream_t stream) {
    const float* x    = (const float*)d_in[0];
    const int*   ei   = (const int*)d_in[1];
    const float* fc_w = (const float*)d_in[2];
    const float* fc_b = (const float*)d_in[3];
    const float* c1w  = (const float*)d_in[4];
    const float* c1b  = (const float*)d_in[5];
    const float* c2w  = (const float*)d_in[6];
    const float* c2b  = (const float*)d_in[7];
    const float* nw   = (const float*)d_in[8];
    const float* nb   = (const float*)d_in[9];
    const float* ew   = (const float*)d_in[10];
    const float* eb   = (const float*)d_in[11];
    const int* row = ei;        // edge_index[0]
    const int* col = ei + EE;   // edge_index[1]

    // workspace layout (4B units): ~47 MB total
    constexpr int NP = 100352;
    float* ws   = (float*)d_ws;
    float* dinv = ws;                               // NP
    int*   bc   = (int*)(ws + NP);                  // NP
    int*   gcur = (int*)(ws + 2 * NP);              // 1024
    int*   ebuf = (int*)(ws + 2 * NP + 1024);       // NBUCK*CAP (even count)
    float* A    = ws + 2 * NP + 1024 + NBUCK * CAP; // h [N*HID] f32
    unsigned short* Bbf = (unsigned short*)(A + (size_t)NN * HID);  // md bf16 (8B-aligned)
    float* ssrc = A;                                // alias: A dead after 2nd k_mm
    float* sdst = A + NP;

    float* out_edge = (float*)d_out;
    float* out_node = out_edge + EE;

    const int nbG = (NN + 63) / 64;             // 1563 GEMM tiles (64 rows each)
    const int nbC = (EE + CHUNK - 1) / CHUNK;   // 391 multisplit chunks
    const int nbQ = (EE / 4 + 255) / 256;       // 1563 edge-quad blocks

    // ---- bucketize + in-place node sort (builds CSR + dinv) ----
    k_zero    <<<(NBUCK + 255) / 256, 256, 0, stream>>>(gcur, NBUCK);
    k_bscatter<<<nbC, 256, 0, stream>>>(row, col, gcur, ebuf);
    k_bsortip <<<NBUCK, 256, 0, stream>>>(gcur, ebuf, bc, dinv);

    // ---- fc, conv1 transform, conv1 gather ----
    k_fc    <<<nbG, 256, 0, stream>>>(x, fc_w, fc_b, A);
    k_mm    <<<nbG, 256, 0, stream>>>(A, c1w, dinv, Bbf);
    k_gather<<<2048, 256, 0, stream>>>(Bbf, ebuf, bc, dinv, c1b, A);

    // ---- conv2 transform + gather fused with scores ----
    k_mm      <<<nbG, 256, 0, stream>>>(A, c2w, dinv, Bbf);
    k_gather2s<<<2048, 256, 0, stream>>>(Bbf, ebuf, bc, dinv, c2b,
                                         nw, nb, ew, out_node, ssrc, sdst);

    // ---- edge scores ----
    k_edge<<<nbQ, 256, 0, stream>>>((const int4*)row, (const int4*)col,
                                    ssrc, sdst, eb, (float4*)out_edge);
}